// Round 11
// baseline (138.369 us; speedup 1.0000x reference)
//
#include <hip/hip_runtime.h>
#include <stdint.h>
#include <stddef.h>

// Match numpy float32 rounding: forbid fma contraction in all float math below.
#pragma clang fp contract(off)

#define N8   819200u
#define N16  204800u
#define N32  51200u
#define NTOT 1075200u
#define TOPK 2048
#define CAND_MAX 8192
#define NBIN 8192u
#define BINSHIFT 10
#define NMS_THR 0.4f
#define DET_THR 0.5f

// ws byte offsets
#define OFF_HIST   0u        // u32[8192]    32KB
#define OFF_META   32768u    // u32[16]
#define OFF_CAND   32832u    // u64[8192]    64KB
#define OFF_TIDX   98368u    // u32[2048]
#define OFF_TCONF  106560u   // f32[2048]
#define OFF_BOX    114752u   // f32[2048*4]  (16B aligned)
#define OFF_DIAGT  147520u   // u32[32][64]  8KB, [rowk][chunk]
#define OFF_SUPPT  155968u   // u32[64][32][64] = 512KB, [chunk][row][word]

__device__ __forceinline__ float load_conf(unsigned a, const float* __restrict__ s8,
                                           const float* __restrict__ s16,
                                           const float* __restrict__ s32) {
  if (a < N8) return s8[a];
  if (a < N8 + N16) return s16[a - N8];
  return s32[a - (N8 + N16)];
}

__device__ __forceinline__ void decode(unsigned a,
    const float* __restrict__ b8, const float* __restrict__ l8,
    const float* __restrict__ b16, const float* __restrict__ l16,
    const float* __restrict__ b32, const float* __restrict__ l32,
    float& cx, float& cy, float& s, const float*& bb, const float*& lm) {
  if (a < N8) {
    unsigned cell = a >> 1;
    cx = (float)((cell % 640u) * 8u); cy = (float)((cell / 640u) * 8u);
    s = 8.f; bb = b8 + (size_t)a * 4; lm = l8 + (size_t)a * 10;
  } else if (a < N8 + N16) {
    unsigned loc = a - N8; unsigned cell = loc >> 1;
    cx = (float)((cell % 320u) * 16u); cy = (float)((cell / 320u) * 16u);
    s = 16.f; bb = b16 + (size_t)loc * 4; lm = l16 + (size_t)loc * 10;
  } else {
    unsigned loc = a - (N8 + N16); unsigned cell = loc >> 1;
    cx = (float)((cell % 160u) * 32u); cy = (float)((cell / 160u) * 32u);
    s = 32.f; bb = b32 + (size_t)loc * 4; lm = l32 + (size_t)loc * 10;
  }
}

// K1: histogram of conf>=0.5 on 13-bit prefix of (bits - bits(0.5))
__global__ void k_hist(const float* __restrict__ s8, const float* __restrict__ s16,
                       const float* __restrict__ s32, unsigned* __restrict__ hist) {
  unsigned i = blockIdx.x * blockDim.x + threadIdx.x;
  unsigned st = gridDim.x * blockDim.x;
  for (unsigned a = i; a < NTOT; a += st) {
    float c = load_conf(a, s8, s16, s32);
    if (c >= DET_THR) {
      unsigned v = (__float_as_uint(c) - 0x3F000000u) >> BINSHIFT;
      if (v > NBIN - 1u) v = NBIN - 1u;
      atomicAdd(&hist[v], 1u);
    }
  }
}

// K2: find cutoff prefix (smallest p with suffix-count >= TOPK); single WG
__global__ void __launch_bounds__(1024) k_scan(const unsigned* __restrict__ hist,
                                               unsigned* __restrict__ meta) {
  __shared__ unsigned suf[1024];
  int t = threadIdx.x;
  const unsigned* hp = hist + (size_t)t * 8;
  unsigned s = 0;
  for (int b = 0; b < 8; b++) s += hp[b];
  suf[t] = s;
  __syncthreads();
  for (int d = 1; d < 1024; d <<= 1) {
    unsigned v = (t + d < 1024) ? suf[t + d] : 0u;
    __syncthreads();
    suf[t] += v;
    __syncthreads();
  }
  unsigned total = suf[0];
  unsigned mine = suf[t];
  unsigned nxt = (t < 1023) ? suf[t + 1] : 0u;
  if (total < (unsigned)TOPK) {
    if (t == 0) { meta[0] = 0u; meta[2] = total; }
    return;
  }
  if (mine >= (unsigned)TOPK && nxt < (unsigned)TOPK) {
    unsigned run = nxt, cut = (unsigned)t * 8u;
    for (int b = 7; b >= 0; b--) {
      run += hp[b];
      if (run >= (unsigned)TOPK) { cut = (unsigned)t * 8u + (unsigned)b; break; }
    }
    meta[0] = cut; meta[2] = total;
  }
}

// K3: compact candidates (>= cutoff prefix) as 64-bit sort keys
__global__ void k_compact(const float* __restrict__ s8, const float* __restrict__ s16,
                          const float* __restrict__ s32, unsigned* __restrict__ meta,
                          unsigned long long* __restrict__ cand) {
  unsigned cut = meta[0];
  unsigned i = blockIdx.x * blockDim.x + threadIdx.x;
  unsigned st = gridDim.x * blockDim.x;
  for (unsigned a = i; a < NTOT; a += st) {
    float c = load_conf(a, s8, s16, s32);
    if (c >= DET_THR) {
      unsigned b = __float_as_uint(c);
      unsigned v = (b - 0x3F000000u) >> BINSHIFT;
      if (v >= cut) {
        unsigned pos = atomicAdd(&meta[3], 1u);
        if (pos < (unsigned)CAND_MAX)
          cand[pos] = ((unsigned long long)b << 32) |
                      (unsigned long long)(0xFFFFFFFFu - a);
      }
    }
  }
}

// K4: rank-and-scatter. Keys unique -> rank(x)=#{y>x} is a permutation.
__global__ void __launch_bounds__(256) k_rank(
    const unsigned long long* __restrict__ cand, const unsigned* __restrict__ meta,
    const float* __restrict__ b8, const float* __restrict__ l8,
    const float* __restrict__ b16, const float* __restrict__ l16,
    const float* __restrict__ b32, const float* __restrict__ l32,
    const float* __restrict__ dsp,
    unsigned* __restrict__ tidx, float* __restrict__ tconf, float* __restrict__ box) {
  unsigned count = meta[3];
  if (count > (unsigned)CAND_MAX) count = (unsigned)CAND_MAX;
  unsigned wave = blockIdx.x * 4u + (threadIdx.x >> 6);
  unsigned lane = threadIdx.x & 63u;
  if (wave >= count) return;
  unsigned long long my = cand[wave];
  unsigned cnt = 0;
  for (unsigned i = lane; i < count; i += 64u)
    cnt += (cand[i] > my) ? 1u : 0u;
  for (int d = 32; d > 0; d >>= 1) cnt += __shfl_down(cnt, d);
  if (lane == 0 && cnt < (unsigned)TOPK) {
    unsigned r = cnt;
    unsigned a = 0xFFFFFFFFu - (unsigned)(my & 0xFFFFFFFFull);
    float conf = __uint_as_float((unsigned)(my >> 32));
    float cx, cy, s; const float* bb; const float* lm;
    decode(a, b8, l8, b16, l16, b32, l32, cx, cy, s, bb, lm);
    float ds = dsp[0];
    float b0 = bb[0] * s, b1 = bb[1] * s, b2 = bb[2] * s, b3 = bb[3] * s;
    box[r * 4 + 0] = (cx - b0) / ds;
    box[r * 4 + 1] = (cy - b1) / ds;
    box[r * 4 + 2] = (cx + b2) / ds;
    box[r * 4 + 3] = (cy + b3) / ds;
    tidx[r] = a; tconf[r] = conf;
  }
}

// K5: suppression matrix for multi-wave NMS: supp_t[chunk i>>5][row i&31][word],
// bit[i][j] = (iou > thr) && (j > i). Also diagT[i&31][i>>5] = the u32 word
// j in [32*(i>>5), 32*(i>>5)+32) of row i (the chunk-diagonal word).
__global__ void __launch_bounds__(256) k_supp(const float* __restrict__ box,
                                              unsigned long long* __restrict__ supp64,
                                              unsigned* __restrict__ diagT) {
  int i = blockIdx.x;
  const float4 bi = ((const float4*)box)[i];
  float ai = fmaxf(bi.z - bi.x, 0.f) * fmaxf(bi.w - bi.y, 0.f);
  int tid = threadIdx.x;
  int lane = tid & 63, wv = tid >> 6;
  int c = i >> 5, k = i & 31;
  for (int base = 0; base < TOPK; base += 256) {
    int j = base + tid;
    const float4 bj = ((const float4*)box)[j];
    float aj = fmaxf(bj.z - bj.x, 0.f) * fmaxf(bj.w - bj.y, 0.f);
    float ltx = fmaxf(bi.x, bj.x), lty = fmaxf(bi.y, bj.y);
    float rbx = fminf(bi.z, bj.z), rby = fminf(bi.w, bj.w);
    float w = fmaxf(rbx - ltx, 0.f), h = fmaxf(rby - lty, 0.f);
    float inter = w * h;
    float iou = inter / (ai + aj - inter + 1e-9f);
    bool pred = (iou > NMS_THR) && (j > i);
    unsigned long long word = __ballot(pred);
    int w64 = (base >> 6) + wv;
    if (lane == 0) {
      // supp64 layout: [chunk][row][word64] = c*1024 + k*32 + w64 (u64 units)
      supp64[(size_t)c * 1024 + k * 32 + w64] = word;
      if (w64 == (i >> 6))
        diagT[k * 64 + c] = (unsigned)(word >> (((i >> 5) & 1) * 32));
    }
  }
}

// K6: greedy NMS with 8 waves + output decode/write (512 threads).
// Per chunk ch (32 rows x 64 colwords = 8KB): wave v owns rows v*4..v*4+3;
// lane l: row r=v*4+(l>>4), words 4g..4g+3 (g=l&15), one dwordx4/lane,
// prefetched 4 chunks deep (independent of keep state).
// Serial closure on wave 0: gather next-word contributions from the 8
// per-wave register accumulators (via LDS wacc), readlane+SALU bit chain
// over preloaded diag VGPRs, publish keep word via LDS. All waves then mask
// their rows by the keep word, shfl_xor OR-reduce the 4 rows, and accumulate
// into per-wave uint4 register accumulator A. 2 barriers/chunk.
// NOTE: STEP's internal chunk var is `ch` — must NOT shadow the loop var `c`
// (R10 bug: `int c = (c+0)` self-init UB).
__global__ void __launch_bounds__(512) k_nms_out(
    const unsigned* __restrict__ supp_t, const unsigned* __restrict__ diagT,
    const unsigned* __restrict__ meta,
    const unsigned* __restrict__ tidx, const float* __restrict__ tconf,
    const float* __restrict__ b8, const float* __restrict__ l8,
    const float* __restrict__ b16, const float* __restrict__ l16,
    const float* __restrict__ b32, const float* __restrict__ l32,
    const float* __restrict__ dsp, float* __restrict__ out) {
  __shared__ unsigned keepw[64];
  __shared__ unsigned wacc[8];
  int tid = threadIdx.x;
  int v = tid >> 6, l = tid & 63;
  unsigned count = meta[3];
  if (count > (unsigned)TOPK) count = (unsigned)TOPK;
  if (tid < 8) wacc[tid] = 0u;
  // diag preload on wave 0: dg[k] lane ch = diag word of row 32*ch+k
  unsigned dg[32];
  if (v == 0) {
#pragma unroll
    for (int k = 0; k < 32; k++) dg[k] = diagT[k * 64 + l];
  }
  int r = v * 4 + (l >> 4);   // row in chunk (0..31)
  int g = l & 15;             // word group: words 4g..4g+3
  const uint4* bp = (const uint4*)supp_t + ((size_t)r * 16 + g);
  // chunk stride = 2048 u32 = 512 uint4
  uint4 P0 = bp[0 * 512], P1 = bp[1 * 512], P2 = bp[2 * 512], P3 = bp[3 * 512];
  uint4 A; A.x = 0u; A.y = 0u; A.z = 0u; A.w = 0u;
  __syncthreads();

#define STEP(PP, CC)                                                          \
  {                                                                           \
    const int ch = (CC);                                                      \
    if (v == 0) {                                                             \
      unsigned app = (l < 8) ? wacc[l] : 0u;                                  \
      app |= __shfl_xor(app, 1);                                              \
      app |= __shfl_xor(app, 2);                                              \
      app |= __shfl_xor(app, 4);                                              \
      unsigned appl = __builtin_amdgcn_readlane(app, 0);                      \
      unsigned lo = (unsigned)ch * 32u;                                       \
      unsigned init = (count >= lo + 32u) ? 0xFFFFFFFFu                       \
                    : (count <= lo ? 0u : ((1u << (count - lo)) - 1u));       \
      unsigned w = init & ~appl;                                              \
      _Pragma("unroll") for (int k = 0; k < 32; k++) {                        \
        unsigned d = __builtin_amdgcn_readlane(dg[k], ch);                    \
        w &= ~(((w >> k) & 1u) ? d : 0u);                                     \
      }                                                                       \
      if (l == 0) keepw[ch] = w;                                              \
    }                                                                         \
    __syncthreads();                                                          \
    unsigned wc = keepw[ch];                                                  \
    unsigned m = 0u - ((wc >> r) & 1u);                                       \
    unsigned x0 = PP.x & m, x1 = PP.y & m, x2 = PP.z & m, x3 = PP.w & m;      \
    x0 |= __shfl_xor(x0, 16); x1 |= __shfl_xor(x1, 16);                       \
    x2 |= __shfl_xor(x2, 16); x3 |= __shfl_xor(x3, 16);                       \
    x0 |= __shfl_xor(x0, 32); x1 |= __shfl_xor(x1, 32);                       \
    x2 |= __shfl_xor(x2, 32); x3 |= __shfl_xor(x3, 32);                       \
    A.x |= x0; A.y |= x1; A.z |= x2; A.w |= x3;                               \
    if (ch + 4 < 64) PP = bp[(size_t)(ch + 4) * 512];                         \
    {                                                                         \
      const int nc = ch + 1;                                                  \
      if (nc < 64 && g == (nc >> 2) && (l >> 4) == 0) {                       \
        const int sel = nc & 3;                                               \
        unsigned comp = (sel == 0) ? A.x : (sel == 1) ? A.y                   \
                       : (sel == 2) ? A.z : A.w;                              \
        wacc[v] = comp;                                                       \
      }                                                                       \
    }                                                                         \
    __syncthreads();                                                          \
  }

#pragma unroll 1
  for (int c = 0; c < 64; c += 4) {
    STEP(P0, c + 0)
    STEP(P1, c + 1)
    STEP(P2, c + 2)
    STEP(P3, c + 3)
  }
#undef STEP

  float ds = dsp[0];
  for (int rr = tid; rr < TOPK; rr += 512) {
    bool kept = (keepw[rr >> 5] >> (rr & 31)) & 1u;
    float o[15];
    if (kept) {
      unsigned a = tidx[rr];
      float cx, cy, s; const float* bb; const float* lm;
      decode(a, b8, l8, b16, l16, b32, l32, cx, cy, s, bb, lm);
      o[0] = tconf[rr];
      float b0 = bb[0] * s, b1 = bb[1] * s, b2 = bb[2] * s, b3 = bb[3] * s;
      o[1] = (cx - b0) / ds;
      o[2] = (cy - b1) / ds;
      o[3] = (cx + b2) / ds;
      o[4] = (cy + b3) / ds;
      for (int p = 0; p < 5; p++) {
        float lx = lm[2 * p] * s, ly = lm[2 * p + 1] * s;
        o[5 + 2 * p] = (cx + lx) / ds;
        o[6 + 2 * p] = (cy + ly) / ds;
      }
    } else {
      for (int cc = 0; cc < 15; cc++) o[cc] = 0.f;
    }
    for (int cc = 0; cc < 15; cc++) out[(size_t)rr * 15 + cc] = o[cc];
  }
}

extern "C" void kernel_launch(void* const* d_in, const int* in_sizes, int n_in,
                              void* d_out, int out_size, void* d_ws, size_t ws_size,
                              hipStream_t stream) {
  const float* s8  = (const float*)d_in[0];
  const float* b8  = (const float*)d_in[1];
  const float* l8  = (const float*)d_in[2];
  const float* s16 = (const float*)d_in[3];
  const float* b16 = (const float*)d_in[4];
  const float* l16 = (const float*)d_in[5];
  const float* s32 = (const float*)d_in[6];
  const float* b32 = (const float*)d_in[7];
  const float* l32 = (const float*)d_in[8];
  const float* dsp = (const float*)d_in[9];
  char* ws = (char*)d_ws;
  unsigned* hist = (unsigned*)(ws + OFF_HIST);
  unsigned* meta = (unsigned*)(ws + OFF_META);
  unsigned long long* cand = (unsigned long long*)(ws + OFF_CAND);
  unsigned* tidx = (unsigned*)(ws + OFF_TIDX);
  float* tconf = (float*)(ws + OFF_TCONF);
  float* box = (float*)(ws + OFF_BOX);
  unsigned* diagT = (unsigned*)(ws + OFF_DIAGT);
  unsigned* supp_t = (unsigned*)(ws + OFF_SUPPT);
  float* out = (float*)d_out;

  hipMemsetAsync(ws, 0, OFF_META + 64, stream);  // hist + meta
  k_hist<<<2048, 256, 0, stream>>>(s8, s16, s32, hist);
  k_scan<<<1, 1024, 0, stream>>>(hist, meta);
  k_compact<<<2048, 256, 0, stream>>>(s8, s16, s32, meta, cand);
  k_rank<<<CAND_MAX / 4, 256, 0, stream>>>(cand, meta, b8, l8, b16, l16, b32, l32,
                                           dsp, tidx, tconf, box);
  k_supp<<<TOPK, 256, 0, stream>>>(box, (unsigned long long*)supp_t, diagT);
  k_nms_out<<<1, 512, 0, stream>>>(supp_t, diagT, meta, tidx, tconf,
                                   b8, l8, b16, l16, b32, l32, dsp, out);
}

// Round 12
// 137.221 us; speedup vs baseline: 1.0084x; 1.0084x over previous
//
#include <hip/hip_runtime.h>
#include <stdint.h>
#include <stddef.h>

// Match numpy float32 rounding: forbid fma contraction in all float math below.
#pragma clang fp contract(off)

#define N8   819200u
#define N16  204800u
#define N32  51200u
#define NTOT 1075200u
#define TOPK 2048
#define CAND_MAX 8192
#define NBIN 8192u
#define BINSHIFT 10
#define NMS_THR 0.4f
#define DET_THR 0.5f

// ws byte offsets
#define OFF_HIST   0u        // u32[8192]    32KB
#define OFF_META   32768u    // u32[16]
#define OFF_CAND   32832u    // u64[8192]    64KB
#define OFF_TIDX   98368u    // u32[2048]
#define OFF_TCONF  106560u   // f32[2048]
#define OFF_BOX    114752u   // f32[2048*4]  (16B aligned)
#define OFF_DIAGT  147520u   // u32[32][64]  8KB, [rowk][chunk]
#define OFF_SUPPT  155968u   // u32[64][32][64] = 512KB, [chunk][row][word]

// LDS-only barrier: orders LDS ops (lgkmcnt) but leaves global loads in
// flight across the barrier (avoids __syncthreads' implicit vmcnt(0) drain,
// which killed the prefetch pipeline in R11).
#define BAR_LDS() asm volatile("s_waitcnt lgkmcnt(0)\n\ts_barrier" ::: "memory")

__device__ __forceinline__ float load_conf(unsigned a, const float* __restrict__ s8,
                                           const float* __restrict__ s16,
                                           const float* __restrict__ s32) {
  if (a < N8) return s8[a];
  if (a < N8 + N16) return s16[a - N8];
  return s32[a - (N8 + N16)];
}

__device__ __forceinline__ void decode(unsigned a,
    const float* __restrict__ b8, const float* __restrict__ l8,
    const float* __restrict__ b16, const float* __restrict__ l16,
    const float* __restrict__ b32, const float* __restrict__ l32,
    float& cx, float& cy, float& s, const float*& bb, const float*& lm) {
  if (a < N8) {
    unsigned cell = a >> 1;
    cx = (float)((cell % 640u) * 8u); cy = (float)((cell / 640u) * 8u);
    s = 8.f; bb = b8 + (size_t)a * 4; lm = l8 + (size_t)a * 10;
  } else if (a < N8 + N16) {
    unsigned loc = a - N8; unsigned cell = loc >> 1;
    cx = (float)((cell % 320u) * 16u); cy = (float)((cell / 320u) * 16u);
    s = 16.f; bb = b16 + (size_t)loc * 4; lm = l16 + (size_t)loc * 10;
  } else {
    unsigned loc = a - (N8 + N16); unsigned cell = loc >> 1;
    cx = (float)((cell % 160u) * 32u); cy = (float)((cell / 160u) * 32u);
    s = 32.f; bb = b32 + (size_t)loc * 4; lm = l32 + (size_t)loc * 10;
  }
}

// K1: histogram of conf>=0.5 on 13-bit prefix of (bits - bits(0.5))
__global__ void k_hist(const float* __restrict__ s8, const float* __restrict__ s16,
                       const float* __restrict__ s32, unsigned* __restrict__ hist) {
  unsigned i = blockIdx.x * blockDim.x + threadIdx.x;
  unsigned st = gridDim.x * blockDim.x;
  for (unsigned a = i; a < NTOT; a += st) {
    float c = load_conf(a, s8, s16, s32);
    if (c >= DET_THR) {
      unsigned v = (__float_as_uint(c) - 0x3F000000u) >> BINSHIFT;
      if (v > NBIN - 1u) v = NBIN - 1u;
      atomicAdd(&hist[v], 1u);
    }
  }
}

// K2: find cutoff prefix (smallest p with suffix-count >= TOPK); single WG
__global__ void __launch_bounds__(1024) k_scan(const unsigned* __restrict__ hist,
                                               unsigned* __restrict__ meta) {
  __shared__ unsigned suf[1024];
  int t = threadIdx.x;
  const unsigned* hp = hist + (size_t)t * 8;
  unsigned s = 0;
  for (int b = 0; b < 8; b++) s += hp[b];
  suf[t] = s;
  __syncthreads();
  for (int d = 1; d < 1024; d <<= 1) {
    unsigned v = (t + d < 1024) ? suf[t + d] : 0u;
    __syncthreads();
    suf[t] += v;
    __syncthreads();
  }
  unsigned total = suf[0];
  unsigned mine = suf[t];
  unsigned nxt = (t < 1023) ? suf[t + 1] : 0u;
  if (total < (unsigned)TOPK) {
    if (t == 0) { meta[0] = 0u; meta[2] = total; }
    return;
  }
  if (mine >= (unsigned)TOPK && nxt < (unsigned)TOPK) {
    unsigned run = nxt, cut = (unsigned)t * 8u;
    for (int b = 7; b >= 0; b--) {
      run += hp[b];
      if (run >= (unsigned)TOPK) { cut = (unsigned)t * 8u + (unsigned)b; break; }
    }
    meta[0] = cut; meta[2] = total;
  }
}

// K3: compact candidates (>= cutoff prefix) as 64-bit sort keys
__global__ void k_compact(const float* __restrict__ s8, const float* __restrict__ s16,
                          const float* __restrict__ s32, unsigned* __restrict__ meta,
                          unsigned long long* __restrict__ cand) {
  unsigned cut = meta[0];
  unsigned i = blockIdx.x * blockDim.x + threadIdx.x;
  unsigned st = gridDim.x * blockDim.x;
  for (unsigned a = i; a < NTOT; a += st) {
    float c = load_conf(a, s8, s16, s32);
    if (c >= DET_THR) {
      unsigned b = __float_as_uint(c);
      unsigned v = (b - 0x3F000000u) >> BINSHIFT;
      if (v >= cut) {
        unsigned pos = atomicAdd(&meta[3], 1u);
        if (pos < (unsigned)CAND_MAX)
          cand[pos] = ((unsigned long long)b << 32) |
                      (unsigned long long)(0xFFFFFFFFu - a);
      }
    }
  }
}

// K4: rank-and-scatter. Keys unique -> rank(x)=#{y>x} is a permutation.
__global__ void __launch_bounds__(256) k_rank(
    const unsigned long long* __restrict__ cand, const unsigned* __restrict__ meta,
    const float* __restrict__ b8, const float* __restrict__ l8,
    const float* __restrict__ b16, const float* __restrict__ l16,
    const float* __restrict__ b32, const float* __restrict__ l32,
    const float* __restrict__ dsp,
    unsigned* __restrict__ tidx, float* __restrict__ tconf, float* __restrict__ box) {
  unsigned count = meta[3];
  if (count > (unsigned)CAND_MAX) count = (unsigned)CAND_MAX;
  unsigned wave = blockIdx.x * 4u + (threadIdx.x >> 6);
  unsigned lane = threadIdx.x & 63u;
  if (wave >= count) return;
  unsigned long long my = cand[wave];
  unsigned cnt = 0;
  for (unsigned i = lane; i < count; i += 64u)
    cnt += (cand[i] > my) ? 1u : 0u;
  for (int d = 32; d > 0; d >>= 1) cnt += __shfl_down(cnt, d);
  if (lane == 0 && cnt < (unsigned)TOPK) {
    unsigned r = cnt;
    unsigned a = 0xFFFFFFFFu - (unsigned)(my & 0xFFFFFFFFull);
    float conf = __uint_as_float((unsigned)(my >> 32));
    float cx, cy, s; const float* bb; const float* lm;
    decode(a, b8, l8, b16, l16, b32, l32, cx, cy, s, bb, lm);
    float ds = dsp[0];
    float b0 = bb[0] * s, b1 = bb[1] * s, b2 = bb[2] * s, b3 = bb[3] * s;
    box[r * 4 + 0] = (cx - b0) / ds;
    box[r * 4 + 1] = (cy - b1) / ds;
    box[r * 4 + 2] = (cx + b2) / ds;
    box[r * 4 + 3] = (cy + b3) / ds;
    tidx[r] = a; tconf[r] = conf;
  }
}

// K5: suppression matrix for multi-wave NMS: supp_t[chunk i>>5][row i&31][word],
// bit[i][j] = (iou > thr) && (j > i). Also diagT[i&31][i>>5] = the u32 word
// j in [32*(i>>5), 32*(i>>5)+32) of row i (the chunk-diagonal word).
__global__ void __launch_bounds__(256) k_supp(const float* __restrict__ box,
                                              unsigned long long* __restrict__ supp64,
                                              unsigned* __restrict__ diagT) {
  int i = blockIdx.x;
  const float4 bi = ((const float4*)box)[i];
  float ai = fmaxf(bi.z - bi.x, 0.f) * fmaxf(bi.w - bi.y, 0.f);
  int tid = threadIdx.x;
  int lane = tid & 63, wv = tid >> 6;
  int c = i >> 5, k = i & 31;
  for (int base = 0; base < TOPK; base += 256) {
    int j = base + tid;
    const float4 bj = ((const float4*)box)[j];
    float aj = fmaxf(bj.z - bj.x, 0.f) * fmaxf(bj.w - bj.y, 0.f);
    float ltx = fmaxf(bi.x, bj.x), lty = fmaxf(bi.y, bj.y);
    float rbx = fminf(bi.z, bj.z), rby = fminf(bi.w, bj.w);
    float w = fmaxf(rbx - ltx, 0.f), h = fmaxf(rby - lty, 0.f);
    float inter = w * h;
    float iou = inter / (ai + aj - inter + 1e-9f);
    bool pred = (iou > NMS_THR) && (j > i);
    unsigned long long word = __ballot(pred);
    int w64 = (base >> 6) + wv;
    if (lane == 0) {
      // supp64 layout: [chunk][row][word64] = c*1024 + k*32 + w64 (u64 units)
      supp64[(size_t)c * 1024 + k * 32 + w64] = word;
      if (w64 == (i >> 6))
        diagT[k * 64 + c] = (unsigned)(word >> (((i >> 5) & 1) * 32));
    }
  }
}

// K6: greedy NMS with 8 waves + output decode/write (512 threads).
// Per chunk ch: wave v owns rows v*4..v*4+3; lane l: row r=v*4+(l>>4),
// words 4g..4g+3 (g=l&15), one dwordx4/lane, prefetched 8 chunks deep.
// Raw LDS-only barriers (BAR_LDS) keep the global prefetch loads in flight
// across chunks (no vmcnt(0) drain). Serial closure on wave 0 reads a single
// LDS word nextw[ch] (accumulated by per-wave ds atomicOr), runs the
// readlane+SALU bit chain over preloaded diag VGPRs, publishes keepw[ch].
// All waves mask their rows, shfl_xor OR-reduce, accumulate into per-wave
// uint4 A, and one lane per wave ORs A's word ch+1 into nextw[ch+1].
__global__ void __launch_bounds__(512) k_nms_out(
    const unsigned* __restrict__ supp_t, const unsigned* __restrict__ diagT,
    const unsigned* __restrict__ meta,
    const unsigned* __restrict__ tidx, const float* __restrict__ tconf,
    const float* __restrict__ b8, const float* __restrict__ l8,
    const float* __restrict__ b16, const float* __restrict__ l16,
    const float* __restrict__ b32, const float* __restrict__ l32,
    const float* __restrict__ dsp, float* __restrict__ out) {
  __shared__ unsigned keepw[64];
  __shared__ unsigned nextw[64];
  int tid = threadIdx.x;
  int v = tid >> 6, l = tid & 63;
  unsigned count = meta[3];
  if (count > (unsigned)TOPK) count = (unsigned)TOPK;
  if (tid < 64) nextw[tid] = 0u;
  // diag preload on wave 0: dg[k] lane ch = diag word of row 32*ch+k
  unsigned dg[32];
  if (v == 0) {
#pragma unroll
    for (int k = 0; k < 32; k++) dg[k] = diagT[k * 64 + l];
  }
  int r = v * 4 + (l >> 4);   // row in chunk (0..31)
  int g = l & 15;             // word group: words 4g..4g+3
  const uint4* bp = (const uint4*)supp_t + ((size_t)r * 16 + g);
  // chunk stride = 2048 u32 = 512 uint4; 8-deep prefetch
  uint4 P0 = bp[0 * 512], P1 = bp[1 * 512], P2 = bp[2 * 512], P3 = bp[3 * 512];
  uint4 P4 = bp[4 * 512], P5 = bp[5 * 512], P6 = bp[6 * 512], P7 = bp[7 * 512];
  uint4 A; A.x = 0u; A.y = 0u; A.z = 0u; A.w = 0u;
  BAR_LDS();

#define STEP(PP, CC)                                                          \
  {                                                                           \
    const int ch = (CC);                                                      \
    if (v == 0) {                                                             \
      unsigned app = nextw[ch];                                               \
      unsigned appl = __builtin_amdgcn_readfirstlane(app);                    \
      unsigned lo = (unsigned)ch * 32u;                                       \
      unsigned init = (count >= lo + 32u) ? 0xFFFFFFFFu                       \
                    : (count <= lo ? 0u : ((1u << (count - lo)) - 1u));       \
      unsigned w = init & ~appl;                                              \
      _Pragma("unroll") for (int k = 0; k < 32; k++) {                        \
        unsigned d = __builtin_amdgcn_readlane(dg[k], ch);                    \
        w &= ~(((w >> k) & 1u) ? d : 0u);                                     \
      }                                                                       \
      if (l == 0) keepw[ch] = w;                                              \
    }                                                                         \
    BAR_LDS();                                                                \
    unsigned wc = keepw[ch];                                                  \
    unsigned m = 0u - ((wc >> r) & 1u);                                       \
    unsigned x0 = PP.x & m, x1 = PP.y & m, x2 = PP.z & m, x3 = PP.w & m;      \
    x0 |= __shfl_xor(x0, 16); x1 |= __shfl_xor(x1, 16);                       \
    x2 |= __shfl_xor(x2, 16); x3 |= __shfl_xor(x3, 16);                       \
    x0 |= __shfl_xor(x0, 32); x1 |= __shfl_xor(x1, 32);                       \
    x2 |= __shfl_xor(x2, 32); x3 |= __shfl_xor(x3, 32);                       \
    A.x |= x0; A.y |= x1; A.z |= x2; A.w |= x3;                               \
    if (ch + 8 < 64) PP = bp[(size_t)(ch + 8) * 512];                         \
    {                                                                         \
      const int nc = ch + 1;                                                  \
      if (nc < 64 && g == (nc >> 2) && (l >> 4) == 0) {                       \
        const int sel = nc & 3;                                               \
        unsigned comp = (sel == 0) ? A.x : (sel == 1) ? A.y                   \
                       : (sel == 2) ? A.z : A.w;                              \
        atomicOr(&nextw[nc], comp);                                           \
      }                                                                       \
    }                                                                         \
    BAR_LDS();                                                                \
  }

#pragma unroll 1
  for (int c = 0; c < 64; c += 8) {
    STEP(P0, c + 0)
    STEP(P1, c + 1)
    STEP(P2, c + 2)
    STEP(P3, c + 3)
    STEP(P4, c + 4)
    STEP(P5, c + 5)
    STEP(P6, c + 6)
    STEP(P7, c + 7)
  }
#undef STEP

  float ds = dsp[0];
  for (int rr = tid; rr < TOPK; rr += 512) {
    bool kept = (keepw[rr >> 5] >> (rr & 31)) & 1u;
    float o[15];
    if (kept) {
      unsigned a = tidx[rr];
      float cx, cy, s; const float* bb; const float* lm;
      decode(a, b8, l8, b16, l16, b32, l32, cx, cy, s, bb, lm);
      o[0] = tconf[rr];
      float b0 = bb[0] * s, b1 = bb[1] * s, b2 = bb[2] * s, b3 = bb[3] * s;
      o[1] = (cx - b0) / ds;
      o[2] = (cy - b1) / ds;
      o[3] = (cx + b2) / ds;
      o[4] = (cy + b3) / ds;
      for (int p = 0; p < 5; p++) {
        float lx = lm[2 * p] * s, ly = lm[2 * p + 1] * s;
        o[5 + 2 * p] = (cx + lx) / ds;
        o[6 + 2 * p] = (cy + ly) / ds;
      }
    } else {
      for (int cc = 0; cc < 15; cc++) o[cc] = 0.f;
    }
    for (int cc = 0; cc < 15; cc++) out[(size_t)rr * 15 + cc] = o[cc];
  }
}

extern "C" void kernel_launch(void* const* d_in, const int* in_sizes, int n_in,
                              void* d_out, int out_size, void* d_ws, size_t ws_size,
                              hipStream_t stream) {
  const float* s8  = (const float*)d_in[0];
  const float* b8  = (const float*)d_in[1];
  const float* l8  = (const float*)d_in[2];
  const float* s16 = (const float*)d_in[3];
  const float* b16 = (const float*)d_in[4];
  const float* l16 = (const float*)d_in[5];
  const float* s32 = (const float*)d_in[6];
  const float* b32 = (const float*)d_in[7];
  const float* l32 = (const float*)d_in[8];
  const float* dsp = (const float*)d_in[9];
  char* ws = (char*)d_ws;
  unsigned* hist = (unsigned*)(ws + OFF_HIST);
  unsigned* meta = (unsigned*)(ws + OFF_META);
  unsigned long long* cand = (unsigned long long*)(ws + OFF_CAND);
  unsigned* tidx = (unsigned*)(ws + OFF_TIDX);
  float* tconf = (float*)(ws + OFF_TCONF);
  float* box = (float*)(ws + OFF_BOX);
  unsigned* diagT = (unsigned*)(ws + OFF_DIAGT);
  unsigned* supp_t = (unsigned*)(ws + OFF_SUPPT);
  float* out = (float*)d_out;

  hipMemsetAsync(ws, 0, OFF_META + 64, stream);  // hist + meta
  k_hist<<<2048, 256, 0, stream>>>(s8, s16, s32, hist);
  k_scan<<<1, 1024, 0, stream>>>(hist, meta);
  k_compact<<<2048, 256, 0, stream>>>(s8, s16, s32, meta, cand);
  k_rank<<<CAND_MAX / 4, 256, 0, stream>>>(cand, meta, b8, l8, b16, l16, b32, l32,
                                           dsp, tidx, tconf, box);
  k_supp<<<TOPK, 256, 0, stream>>>(box, (unsigned long long*)supp_t, diagT);
  k_nms_out<<<1, 512, 0, stream>>>(supp_t, diagT, meta, tidx, tconf,
                                   b8, l8, b16, l16, b32, l32, dsp, out);
}

// Round 13
// 130.460 us; speedup vs baseline: 1.0606x; 1.0518x over previous
//
#include <hip/hip_runtime.h>
#include <stdint.h>
#include <stddef.h>

// Match numpy float32 rounding: forbid fma contraction in all float math below.
#pragma clang fp contract(off)

#define N8   819200u
#define N16  204800u
#define N32  51200u
#define NTOT 1075200u
#define TOPK 2048
#define CAND_MAX 8192
#define NBIN 8192u
#define BINSHIFT 10
#define NMS_THR 0.4f
#define DET_THR 0.5f

// ws byte offsets
#define OFF_HIST   0u        // u32[8192]    32KB
#define OFF_META   32768u    // u32[16]
#define OFF_CAND   32832u    // u64[8192]    64KB
#define OFF_TIDX   98368u    // u32[2048]
#define OFF_TCONF  106560u   // f32[2048]
#define OFF_BOX    114752u   // f32[2048*4]  (16B aligned)
#define OFF_DIAGT  147520u   // u32[32][64]  8KB, [rowk][chunk]
#define OFF_SUPPT  155968u   // u32[64][32][64] = 512KB, [chunk][row][word]

__device__ __forceinline__ float load_conf(unsigned a, const float* __restrict__ s8,
                                           const float* __restrict__ s16,
                                           const float* __restrict__ s32) {
  if (a < N8) return s8[a];
  if (a < N8 + N16) return s16[a - N8];
  return s32[a - (N8 + N16)];
}

__device__ __forceinline__ void decode(unsigned a,
    const float* __restrict__ b8, const float* __restrict__ l8,
    const float* __restrict__ b16, const float* __restrict__ l16,
    const float* __restrict__ b32, const float* __restrict__ l32,
    float& cx, float& cy, float& s, const float*& bb, const float*& lm) {
  if (a < N8) {
    unsigned cell = a >> 1;
    cx = (float)((cell % 640u) * 8u); cy = (float)((cell / 640u) * 8u);
    s = 8.f; bb = b8 + (size_t)a * 4; lm = l8 + (size_t)a * 10;
  } else if (a < N8 + N16) {
    unsigned loc = a - N8; unsigned cell = loc >> 1;
    cx = (float)((cell % 320u) * 16u); cy = (float)((cell / 320u) * 16u);
    s = 16.f; bb = b16 + (size_t)loc * 4; lm = l16 + (size_t)loc * 10;
  } else {
    unsigned loc = a - (N8 + N16); unsigned cell = loc >> 1;
    cx = (float)((cell % 160u) * 32u); cy = (float)((cell / 160u) * 32u);
    s = 32.f; bb = b32 + (size_t)loc * 4; lm = l32 + (size_t)loc * 10;
  }
}

// K1: histogram of conf>=0.5 on 13-bit prefix of (bits - bits(0.5))
__global__ void k_hist(const float* __restrict__ s8, const float* __restrict__ s16,
                       const float* __restrict__ s32, unsigned* __restrict__ hist) {
  unsigned i = blockIdx.x * blockDim.x + threadIdx.x;
  unsigned st = gridDim.x * blockDim.x;
  for (unsigned a = i; a < NTOT; a += st) {
    float c = load_conf(a, s8, s16, s32);
    if (c >= DET_THR) {
      unsigned v = (__float_as_uint(c) - 0x3F000000u) >> BINSHIFT;
      if (v > NBIN - 1u) v = NBIN - 1u;
      atomicAdd(&hist[v], 1u);
    }
  }
}

// K2: find cutoff prefix (smallest p with suffix-count >= TOPK); single WG
__global__ void __launch_bounds__(1024) k_scan(const unsigned* __restrict__ hist,
                                               unsigned* __restrict__ meta) {
  __shared__ unsigned suf[1024];
  int t = threadIdx.x;
  const unsigned* hp = hist + (size_t)t * 8;
  unsigned s = 0;
  for (int b = 0; b < 8; b++) s += hp[b];
  suf[t] = s;
  __syncthreads();
  for (int d = 1; d < 1024; d <<= 1) {
    unsigned v = (t + d < 1024) ? suf[t + d] : 0u;
    __syncthreads();
    suf[t] += v;
    __syncthreads();
  }
  unsigned total = suf[0];
  unsigned mine = suf[t];
  unsigned nxt = (t < 1023) ? suf[t + 1] : 0u;
  if (total < (unsigned)TOPK) {
    if (t == 0) { meta[0] = 0u; meta[2] = total; }
    return;
  }
  if (mine >= (unsigned)TOPK && nxt < (unsigned)TOPK) {
    unsigned run = nxt, cut = (unsigned)t * 8u;
    for (int b = 7; b >= 0; b--) {
      run += hp[b];
      if (run >= (unsigned)TOPK) { cut = (unsigned)t * 8u + (unsigned)b; break; }
    }
    meta[0] = cut; meta[2] = total;
  }
}

// K3: compact candidates (>= cutoff prefix) as 64-bit sort keys
__global__ void k_compact(const float* __restrict__ s8, const float* __restrict__ s16,
                          const float* __restrict__ s32, unsigned* __restrict__ meta,
                          unsigned long long* __restrict__ cand) {
  unsigned cut = meta[0];
  unsigned i = blockIdx.x * blockDim.x + threadIdx.x;
  unsigned st = gridDim.x * blockDim.x;
  for (unsigned a = i; a < NTOT; a += st) {
    float c = load_conf(a, s8, s16, s32);
    if (c >= DET_THR) {
      unsigned b = __float_as_uint(c);
      unsigned v = (b - 0x3F000000u) >> BINSHIFT;
      if (v >= cut) {
        unsigned pos = atomicAdd(&meta[3], 1u);
        if (pos < (unsigned)CAND_MAX)
          cand[pos] = ((unsigned long long)b << 32) |
                      (unsigned long long)(0xFFFFFFFFu - a);
      }
    }
  }
}

// K4: rank-and-scatter. Keys unique -> rank(x)=#{y>x} is a permutation.
__global__ void __launch_bounds__(256) k_rank(
    const unsigned long long* __restrict__ cand, const unsigned* __restrict__ meta,
    const float* __restrict__ b8, const float* __restrict__ l8,
    const float* __restrict__ b16, const float* __restrict__ l16,
    const float* __restrict__ b32, const float* __restrict__ l32,
    const float* __restrict__ dsp,
    unsigned* __restrict__ tidx, float* __restrict__ tconf, float* __restrict__ box) {
  unsigned count = meta[3];
  if (count > (unsigned)CAND_MAX) count = (unsigned)CAND_MAX;
  unsigned wave = blockIdx.x * 4u + (threadIdx.x >> 6);
  unsigned lane = threadIdx.x & 63u;
  if (wave >= count) return;
  unsigned long long my = cand[wave];
  unsigned cnt = 0;
  for (unsigned i = lane; i < count; i += 64u)
    cnt += (cand[i] > my) ? 1u : 0u;
  for (int d = 32; d > 0; d >>= 1) cnt += __shfl_down(cnt, d);
  if (lane == 0 && cnt < (unsigned)TOPK) {
    unsigned r = cnt;
    unsigned a = 0xFFFFFFFFu - (unsigned)(my & 0xFFFFFFFFull);
    float conf = __uint_as_float((unsigned)(my >> 32));
    float cx, cy, s; const float* bb; const float* lm;
    decode(a, b8, l8, b16, l16, b32, l32, cx, cy, s, bb, lm);
    float ds = dsp[0];
    float b0 = bb[0] * s, b1 = bb[1] * s, b2 = bb[2] * s, b3 = bb[3] * s;
    box[r * 4 + 0] = (cx - b0) / ds;
    box[r * 4 + 1] = (cy - b1) / ds;
    box[r * 4 + 2] = (cx + b2) / ds;
    box[r * 4 + 3] = (cy + b3) / ds;
    tidx[r] = a; tconf[r] = conf;
  }
}

// K5: suppression matrix: supp[chunk i>>5][row i&31][word64], bit[i][j] =
// (iou > thr) && (j > i). diagT[i&31][i>>5] = chunk-diagonal u32 word.
// NONTEMPORAL stores: written by 2048 blocks across all 8 XCDs; nt keeps the
// lines OUT of the writers' L2s so the single-CU NMS reader gets clean
// L3/HBM hits instead of dirty-remote-L2 snoops (R12 theory: that latency
// was the NMS wall).
__global__ void __launch_bounds__(256) k_supp(const float* __restrict__ box,
                                              unsigned long long* __restrict__ supp64,
                                              unsigned* __restrict__ diagT) {
  int i = blockIdx.x;
  const float4 bi = ((const float4*)box)[i];
  float ai = fmaxf(bi.z - bi.x, 0.f) * fmaxf(bi.w - bi.y, 0.f);
  int tid = threadIdx.x;
  int lane = tid & 63, wv = tid >> 6;
  int c = i >> 5, k = i & 31;
  for (int base = 0; base < TOPK; base += 256) {
    int j = base + tid;
    const float4 bj = ((const float4*)box)[j];
    float aj = fmaxf(bj.z - bj.x, 0.f) * fmaxf(bj.w - bj.y, 0.f);
    float ltx = fmaxf(bi.x, bj.x), lty = fmaxf(bi.y, bj.y);
    float rbx = fminf(bi.z, bj.z), rby = fminf(bi.w, bj.w);
    float w = fmaxf(rbx - ltx, 0.f), h = fmaxf(rby - lty, 0.f);
    float inter = w * h;
    float iou = inter / (ai + aj - inter + 1e-9f);
    bool pred = (iou > NMS_THR) && (j > i);
    unsigned long long word = __ballot(pred);
    int w64 = (base >> 6) + wv;
    if (lane == 0) {
      __builtin_nontemporal_store(word, &supp64[(size_t)c * 1024 + k * 32 + w64]);
      if (w64 == (i >> 6))
        __builtin_nontemporal_store(
            (unsigned)(word >> (((i >> 5) & 1) * 32)), &diagT[k * 64 + c]);
    }
  }
}

// K6: greedy NMS on ONE wave (no barriers/LDS in the loop) + output on 256
// threads. Lane l owns keep word l (j in [32l,32l+32)). Diag preloaded once
// into 32 VGPRs; per-chunk closure = 32 readlane + SALU bit chain; apply =
// 32 v_and_or with scalar masks into 4 independent accumulators.
// Prefetch: 4 chunk buffers as PLAIN dword arrays (T0..T3[32]), fully
// static-indexed (no uint4 => no scratch spill; R6's VGPR=104 proved the
// x4-buffer version spilled). Lane-coalesced: T[k] = supp32[ch*2048+k*64+l].
__global__ void __launch_bounds__(256, 1) k_nms_out(
    const unsigned* __restrict__ supp_t, const unsigned* __restrict__ diagT,
    const unsigned* __restrict__ meta,
    const unsigned* __restrict__ tidx, const float* __restrict__ tconf,
    const float* __restrict__ b8, const float* __restrict__ l8,
    const float* __restrict__ b16, const float* __restrict__ l16,
    const float* __restrict__ b32, const float* __restrict__ l32,
    const float* __restrict__ dsp, float* __restrict__ out) {
  __shared__ unsigned keepw[64];
  int tid = threadIdx.x;
  if (tid < 64) {
    int l = tid;
    unsigned count = meta[3];
    if (count > (unsigned)TOPK) count = (unsigned)TOPK;
    unsigned lo = (unsigned)l * 32u;
    unsigned kw = (count >= lo + 32u) ? 0xFFFFFFFFu
                : (count <= lo ? 0u : ((1u << (count - lo)) - 1u));
    const unsigned* sp = supp_t + l;
    unsigned dg[32];
#pragma unroll
    for (int k = 0; k < 32; k++) dg[k] = diagT[k * 64 + l];
    unsigned T0[32], T1[32], T2[32], T3[32];

#define LOADT(BUF, CH)                                                        \
  _Pragma("unroll") for (int k = 0; k < 32; k++)                              \
      BUF[k] = sp[(size_t)(unsigned)((CH) * 2048 + k * 64)];

    LOADT(T0, 0) LOADT(T1, 1) LOADT(T2, 2) LOADT(T3, 3)

#define STEP(BUF, CC)                                                         \
  {                                                                           \
    const int ch = (CC);                                                      \
    unsigned w = __builtin_amdgcn_readlane(kw, ch);                           \
    _Pragma("unroll") for (int k = 0; k < 32; k++) {                          \
      unsigned d = __builtin_amdgcn_readlane(dg[k], ch);                      \
      w &= ~(((w >> k) & 1u) ? d : 0u);                                       \
    }                                                                         \
    unsigned acc0 = 0u, acc1 = 0u, acc2 = 0u, acc3 = 0u;                      \
    _Pragma("unroll") for (int q = 0; q < 8; q++) {                           \
      unsigned m0 = (unsigned)((int)(w << (31 - (4 * q + 0))) >> 31);         \
      unsigned m1 = (unsigned)((int)(w << (31 - (4 * q + 1))) >> 31);         \
      unsigned m2 = (unsigned)((int)(w << (31 - (4 * q + 2))) >> 31);         \
      unsigned m3 = (unsigned)((int)(w << (31 - (4 * q + 3))) >> 31);         \
      acc0 |= BUF[4 * q + 0] & m0;                                            \
      acc1 |= BUF[4 * q + 1] & m1;                                            \
      acc2 |= BUF[4 * q + 2] & m2;                                            \
      acc3 |= BUF[4 * q + 3] & m3;                                            \
    }                                                                         \
    kw &= ~((acc0 | acc1) | (acc2 | acc3));                                   \
    if (ch + 4 < 64) { LOADT(BUF, ch + 4) }                                   \
  }

#pragma unroll 1
    for (int c = 0; c < 64; c += 4) {
      STEP(T0, c + 0)
      STEP(T1, c + 1)
      STEP(T2, c + 2)
      STEP(T3, c + 3)
    }
#undef LOADT
#undef STEP
    keepw[l] = kw;
  }
  __syncthreads();
  float ds = dsp[0];
  for (int rr = tid; rr < TOPK; rr += 256) {
    bool kept = (keepw[rr >> 5] >> (rr & 31)) & 1u;
    float o[15];
    if (kept) {
      unsigned a = tidx[rr];
      float cx, cy, s; const float* bb; const float* lm;
      decode(a, b8, l8, b16, l16, b32, l32, cx, cy, s, bb, lm);
      o[0] = tconf[rr];
      float b0 = bb[0] * s, b1 = bb[1] * s, b2 = bb[2] * s, b3 = bb[3] * s;
      o[1] = (cx - b0) / ds;
      o[2] = (cy - b1) / ds;
      o[3] = (cx + b2) / ds;
      o[4] = (cy + b3) / ds;
      for (int p = 0; p < 5; p++) {
        float lx = lm[2 * p] * s, ly = lm[2 * p + 1] * s;
        o[5 + 2 * p] = (cx + lx) / ds;
        o[6 + 2 * p] = (cy + ly) / ds;
      }
    } else {
      for (int cc = 0; cc < 15; cc++) o[cc] = 0.f;
    }
    for (int cc = 0; cc < 15; cc++) out[(size_t)rr * 15 + cc] = o[cc];
  }
}

extern "C" void kernel_launch(void* const* d_in, const int* in_sizes, int n_in,
                              void* d_out, int out_size, void* d_ws, size_t ws_size,
                              hipStream_t stream) {
  const float* s8  = (const float*)d_in[0];
  const float* b8  = (const float*)d_in[1];
  const float* l8  = (const float*)d_in[2];
  const float* s16 = (const float*)d_in[3];
  const float* b16 = (const float*)d_in[4];
  const float* l16 = (const float*)d_in[5];
  const float* s32 = (const float*)d_in[6];
  const float* b32 = (const float*)d_in[7];
  const float* l32 = (const float*)d_in[8];
  const float* dsp = (const float*)d_in[9];
  char* ws = (char*)d_ws;
  unsigned* hist = (unsigned*)(ws + OFF_HIST);
  unsigned* meta = (unsigned*)(ws + OFF_META);
  unsigned long long* cand = (unsigned long long*)(ws + OFF_CAND);
  unsigned* tidx = (unsigned*)(ws + OFF_TIDX);
  float* tconf = (float*)(ws + OFF_TCONF);
  float* box = (float*)(ws + OFF_BOX);
  unsigned* diagT = (unsigned*)(ws + OFF_DIAGT);
  unsigned* supp_t = (unsigned*)(ws + OFF_SUPPT);
  float* out = (float*)d_out;

  hipMemsetAsync(ws, 0, OFF_META + 64, stream);  // hist + meta
  k_hist<<<2048, 256, 0, stream>>>(s8, s16, s32, hist);
  k_scan<<<1, 1024, 0, stream>>>(hist, meta);
  k_compact<<<2048, 256, 0, stream>>>(s8, s16, s32, meta, cand);
  k_rank<<<CAND_MAX / 4, 256, 0, stream>>>(cand, meta, b8, l8, b16, l16, b32, l32,
                                           dsp, tidx, tconf, box);
  k_supp<<<TOPK, 256, 0, stream>>>(box, (unsigned long long*)supp_t, diagT);
  k_nms_out<<<1, 256, 0, stream>>>(supp_t, diagT, meta, tidx, tconf,
                                   b8, l8, b16, l16, b32, l32, dsp, out);
}